// Round 13
// baseline (60.071 us; speedup 1.0000x reference)
//
#include <hip/hip_runtime.h>
#include <math.h>

#define NN 4096
#define RCAP 256          // per-row/col bucket capacity (mean 80, max ~130)
#define CPAD 16           // counter stride in ints: one counter per 64B line
#define CR 4              // rows (or cols) per coalesce block, wave per row
#define HS2 1024          // shared LDS hash slots (load ~31%, worst ~55%)
#define NPART 8           // XCD partitions (blockIdx%8 -> XCD round-robin)
#define PROWS (NN / NPART)   // 512 rows per partition
#define NCHK 128          // input chunks per partition

// mysign(|v|) - 0.5 with reference-faithful overflow: e=inf -> NaN
__device__ __forceinline__ float smh(float v) {
    float e = expf(6.0f * fabsf(v));
    return 0.5f * (e - 1.0f) / (e + 1.0f);
}

// Zero row+col counters (rocclr small-fill kernel is latency-bound).
__global__ __launch_bounds__(256) void zero_k(float4* __restrict__ p) {
    p[blockIdx.x * 256 + threadIdx.x] = make_float4(0.f, 0.f, 0.f, 0.f);
}

// XCD-partitioned bucketing: block (p = blockIdx%8, chunk = blockIdx/8)
// scans chunk `chunk` of the input and keeps records with row (resp. col)
// in partition p. All writes to partition p's rowbuf/colbuf slice come from
// one XCD -> lines stay in that XCD's L2 and write-back coalesced.
__global__ __launch_bounds__(256) void bucket_k(
    const int2* __restrict__ edges, const float* __restrict__ weights,
    const float* __restrict__ stat, const int2* __restrict__ edges_c,
    const float* __restrict__ grdt, int* __restrict__ row_cnt,
    int* __restrict__ col_cnt, float4* __restrict__ rowbuf,
    float4* __restrict__ colbuf, int E, int EC) {
    const int p = blockIdx.x & (NPART - 1);
    const int chunk = blockIdx.x >> 3;
    const int total = E + EC;
    const int csz = (total + NCHK - 1) / NCHK;
    const int lo = chunk * csz;
    const int hi = min(lo + csz, total);
    const int rlo = p * PROWS, rhi = rlo + PROWS;
    for (int i = lo + threadIdx.x; i < hi; i += 256) {
        int2 rc; int isC;
        if (i < E) { rc = edges[i]; isC = 0; }
        else { rc = edges_c[i - E]; isC = 1; }
        bool rowHit = (rc.x >= rlo && rc.x < rhi);
        bool colHit = (rc.y >= rlo && rc.y < rhi);
        if (!rowHit && !colHit) continue;
        float4 rec;
        if (isC) { rec.y = grdt[i - E]; rec.z = 0.f; }
        else { rec.y = stat[i]; rec.z = weights[i]; }
        rec.w = 0.f;
        if (rowHit) {
            int pos = atomicAdd(&row_cnt[rc.x * CPAD], 1);
            if (pos < RCAP) {
                rec.x = __int_as_float((rc.y << 1) | isC);   // tag = col
                rowbuf[rc.x * RCAP + pos] = rec;
            }
        }
        if (colHit) {
            int pos = atomicAdd(&col_cnt[rc.y * CPAD], 1);
            if (pos < RCAP) {
                rec.x = __int_as_float((rc.x << 1) | isC);   // tag = row
                colbuf[rc.y * RCAP + pos] = rec;
            }
        }
    }
}

// Col side first: wave per column, LDS hash coalesces duplicate cells
// (scatter-add semantics), sweep v = B*(A-1)+A*W: g += v, nin += smh(v);
// good = clip(g/Nin, -1, 1) NaN-propagating, Nin baseline 2048
// (mysign(0)=0.5 per zero cell). XCD-swizzled to read L2-local slices.
__global__ __launch_bounds__(256) void colgood_k(
    const int* __restrict__ col_cnt, const float4* __restrict__ colbuf,
    float* __restrict__ good_buf, float* __restrict__ good_out) {
    __shared__ int hkey[HS2];
    __shared__ float hA[HS2], hW[HS2], hB[HS2];
    __shared__ float acc1[CR], acc2[CR];
    const int tid = threadIdx.x;
    const int wv = tid >> 6, lane = tid & 63;
    const int j = blockIdx.x;
    const int base = (j & (NPART - 1)) * PROWS + (j >> 3) * CR;
    for (int i = tid; i < HS2; i += 256) {
        hkey[i] = -1; hA[i] = 0.f; hW[i] = 0.f; hB[i] = 0.f;
    }
    if (tid < CR) { acc1[tid] = 0.f; acc2[tid] = 0.f; }
    __syncthreads();
    {   // wave wv owns column base+wv
        int idx = base + wv;
        int cnt = col_cnt[idx * CPAD];
        if (cnt > RCAP) cnt = RCAP;
        for (int i = lane; i < cnt; i += 64) {
            float4 rec = colbuf[idx * RCAP + i];
            int ct = __float_as_int(rec.x);
            int key = (wv << 12) | (ct >> 1);
            int slot = (int)(((unsigned)key * 2654435761u) >> 18) & (HS2 - 1);
            while (true) {
                int prev = atomicCAS(&hkey[slot], -1, key);
                if (prev == -1 || prev == key) break;
                slot = (slot + 1) & (HS2 - 1);
            }
            if (ct & 1) {
                atomicAdd(&hB[slot], rec.y);
            } else {
                atomicAdd(&hA[slot], rec.y);
                atomicAdd(&hW[slot], rec.z);
            }
        }
    }
    __syncthreads();
#pragma unroll
    for (int k = 0; k < HS2 / 256; ++k) {      // 4 slots/thread
        int s = k * 256 + tid;
        int key = hkey[s];
        if (key != -1) {
            float a = hA[s], w = hW[s], b = hB[s];
            float v = b * (a - 1.0f) + a * w;
            if (v != 0.0f) {                   // zero cells: 0 to all sums
                int lc = key >> 12;
                atomicAdd(&acc1[lc], smh(v));  // NaN propagates like ref
                atomicAdd(&acc2[lc], v);       // g (column sum)
            }
        }
    }
    __syncthreads();
    if (tid < CR) {
        float Nin = 2048.0f + acc1[tid];
        float gd = 1.0f;
        if (Nin != 0.0f) {
            float x = acc2[tid] / Nin;
            gd = x < -1.0f ? -1.0f : (x > 1.0f ? 1.0f : x);  // NaN stays NaN
        }
        good_buf[base + tid] = gd;
        good_out[base + tid] = gd;
    }
}

// Row side second: same hash coalesce, but fair is computed inline at the
// sweep (good_buf already final) -- no CSR materialization at all.
// f += 1 - |v - good[c]|/2 over v != 0; fair = clip(f/Nout, 0, 1).
// Last block does the targets gsum.
__global__ __launch_bounds__(256) void rowfair_k(
    const int* __restrict__ row_cnt, const float4* __restrict__ rowbuf,
    const float* __restrict__ good_buf, const int* __restrict__ targets,
    int T, float* __restrict__ out) {
    if (blockIdx.x < NN / CR) {
        __shared__ int hkey[HS2];
        __shared__ float hA[HS2], hW[HS2], hB[HS2];
        __shared__ float acc1[CR], acc2[CR];
        const int tid = threadIdx.x;
        const int wv = tid >> 6, lane = tid & 63;
        const int j = blockIdx.x;
        const int base = (j & (NPART - 1)) * PROWS + (j >> 3) * CR;
        for (int i = tid; i < HS2; i += 256) {
            hkey[i] = -1; hA[i] = 0.f; hW[i] = 0.f; hB[i] = 0.f;
        }
        if (tid < CR) { acc1[tid] = 0.f; acc2[tid] = 0.f; }
        __syncthreads();
        {   // wave wv owns row base+wv
            int idx = base + wv;
            int cnt = row_cnt[idx * CPAD];
            if (cnt > RCAP) cnt = RCAP;
            for (int i = lane; i < cnt; i += 64) {
                float4 rec = rowbuf[idx * RCAP + i];
                int ct = __float_as_int(rec.x);
                int key = (wv << 12) | (ct >> 1);
                int slot = (int)(((unsigned)key * 2654435761u) >> 18) & (HS2 - 1);
                while (true) {
                    int prev = atomicCAS(&hkey[slot], -1, key);
                    if (prev == -1 || prev == key) break;
                    slot = (slot + 1) & (HS2 - 1);
                }
                if (ct & 1) {
                    atomicAdd(&hB[slot], rec.y);
                } else {
                    atomicAdd(&hA[slot], rec.y);
                    atomicAdd(&hW[slot], rec.z);
                }
            }
        }
        __syncthreads();
#pragma unroll
        for (int k = 0; k < HS2 / 256; ++k) {  // 4 slots/thread
            int s = k * 256 + tid;
            int key = hkey[s];
            if (key != -1) {
                float a = hA[s], w = hW[s], b = hB[s];
                float v = b * (a - 1.0f) + a * w;
                if (v != 0.0f) {               // reference mask: V != 0
                    int lr = key >> 12;
                    atomicAdd(&acc1[lr], smh(v));   // NaN propagates
                    atomicAdd(&acc2[lr],
                              1.0f - 0.5f * fabsf(v - good_buf[key & 4095]));
                }
            }
        }
        __syncthreads();
        if (tid < CR) {
            float Nout = 2048.0f + acc1[tid];
            float fair = 1.0f;
            if (Nout != 0.0f) {
                float x = acc2[tid] / Nout;
                fair = x < 0.0f ? 0.0f : (x > 1.0f ? 1.0f : x);  // NaN stays
            }
            out[1 + base + tid] = fair;
        }
    } else {
        float s = 0.f;
        for (int i = threadIdx.x; i < T; i += 256) {
            float gt = good_buf[targets[i]];
            s += (gt == gt) ? gt : 0.0f;   // NaN -> 0
        }
        for (int off = 32; off > 0; off >>= 1) s += __shfl_down(s, off, 64);
        __shared__ float lds[4];
        int lane = threadIdx.x & 63, w = threadIdx.x >> 6;
        if (lane == 0) lds[w] = s;
        __syncthreads();
        if (threadIdx.x == 0) out[0] = lds[0] + lds[1] + lds[2] + lds[3];
    }
}

extern "C" void kernel_launch(void* const* d_in, const int* in_sizes, int n_in,
                              void* d_out, int out_size, void* d_ws, size_t ws_size,
                              hipStream_t stream) {
    const int2*  edges   = (const int2*)d_in[0];
    const float* weights = (const float*)d_in[1];
    const float* stat    = (const float*)d_in[2];
    const int2*  edges_c = (const int2*)d_in[3];
    const float* grdt    = (const float*)d_in[4];
    const int*   targets = (const int*)d_in[5];
    const int E  = in_sizes[1];
    const int EC = in_sizes[4];
    const int T  = in_sizes[5];
    float* out = (float*)d_out;

    int*    row_cnt  = (int*)d_ws;                          // NN*CPAD
    int*    col_cnt  = row_cnt + NN * CPAD;                 // NN*CPAD
    float*  good_buf = (float*)(col_cnt + NN * CPAD);       // NN
    float4* rowbuf   = (float4*)(good_buf + NN);            // NN*RCAP float4
    float4* colbuf   = rowbuf + (size_t)NN * RCAP;          // NN*RCAP float4

    // zero row_cnt+col_cnt: 2*NN*CPAD ints = 512KB = 128 blk * 256 t * 16B
    zero_k<<<2 * NN * CPAD / (256 * 4), 256, 0, stream>>>((float4*)row_cnt);

    bucket_k<<<NPART * NCHK, 256, 0, stream>>>(
        edges, weights, stat, edges_c, grdt, row_cnt, col_cnt,
        rowbuf, colbuf, E, EC);

    colgood_k<<<NN / CR, 256, 0, stream>>>(col_cnt, colbuf, good_buf,
                                           out + 1 + NN);

    rowfair_k<<<NN / CR + 1, 256, 0, stream>>>(row_cnt, rowbuf, good_buf,
                                               targets, T, out);
}